// Round 3
// baseline (172.960 us; speedup 1.0000x reference)
//
#include <hip/hip_runtime.h>
#include <hip/hip_bf16.h>

typedef short bf16x8 __attribute__((ext_vector_type(8)));
typedef float f32x4  __attribute__((ext_vector_type(4)));

__device__ __forceinline__ unsigned cvt2(float a, float b) {
  __hip_bfloat162 h = __float22bfloat162_rn(make_float2(a, b));
  unsigned u; __builtin_memcpy(&u, &h, 4); return u;
}

__device__ __forceinline__ f32x4 MFMA(bf16x8 a, bf16x8 b, f32x4 c) {
  return __builtin_amdgcn_mfma_f32_16x16x32_bf16(a, b, c, 0, 0, 0);
}

// XP: [64 cols][64 h] f32, XOR swizzle at 4-word granule
__device__ __forceinline__ int xp_idx(int n, int h) { return (n << 6) + (h ^ ((n & 7) << 2)); }
// Z: [64 cols][128 k] bf16, XOR swizzle at 8-short (16B) granule
__device__ __forceinline__ int z_idx(int n, int k) { return (n << 7) + (k ^ ((n & 7) << 3)); }

// ---- weight permute + bf16 cast via transposed padded LDS ----
// W'[o][k'] with k' = m*H + h, source w[o][h*40 + m]
__global__ __launch_bounds__(256) void permute_w_kernel(
    const float* __restrict__ w0, const float* __restrict__ w1,
    const float* __restrict__ w2, unsigned short* __restrict__ Wp) {
  __shared__ float rowt[40 * 65];   // [m][h], padded stride 65
  const int b = blockIdx.x;
  const float* src; unsigned short* dst; int K, LZ;
  if (b < 128)      { src = w0 + b * 1600;            dst = Wp + b * 1600;            K = 1600; LZ = 1; }
  else if (b < 256) { int o = b - 128; src = w1 + o * 2560; dst = Wp + 204800 + o * 2560; K = 2560; LZ = 0; }
  else              { int o = b - 256; src = w2 + o * 2560; dst = Wp + 532480 + o * 2560; K = 2560; LZ = 0; }
  for (int i = threadIdx.x; i < (K >> 2); i += 256) {
    float4 v = ((const float4*)src)[i];
    int f = i << 2;
    int h = f / 40, m = f - h * 40;   // src is h-major, m inner; 4 | 40 so no straddle
    rowt[(m + 0) * 65 + h] = v.x;
    rowt[(m + 1) * 65 + h] = v.y;
    rowt[(m + 2) * 65 + h] = v.z;
    rowt[(m + 3) * 65 + h] = v.w;
  }
  __syncthreads();
  for (int i = threadIdx.x; i < (K >> 3); i += 256) {
    const int k = i << 3;
    int m, h;
    if (LZ) { m = k / 40; h = k - m * 40; } else { m = k >> 6; h = k & 63; }
    const float* p = &rowt[m * 65 + h];
    uint4 u;
    u.x = cvt2(p[0], p[1]); u.y = cvt2(p[2], p[3]);
    u.z = cvt2(p[4], p[5]); u.w = cvt2(p[6], p[7]);
    *(uint4*)&dst[k] = u;
  }
}

// ---- fused CIN: 64 columns (4 b x 16 d) per block ----
// L0: BK=64 (25 steps); L1/2: BK=128 (20 steps). A prefetched 1 step ahead in regs.
__global__ __launch_bounds__(256, 2) void cin_kernel(
    const float* __restrict__ x, const unsigned short* __restrict__ Wp,
    const float* __restrict__ bias0, const float* __restrict__ bias1,
    const float* __restrict__ bias2, const float* __restrict__ wl,
    float* __restrict__ out) {
  __shared__ __align__(16) float XP_s[64 * 64];             // X (l0), then P
  __shared__ __align__(16) float XT_s[40 * 64];             // X transposed [m][col]
  __shared__ __align__(16) unsigned short Z_s[2][64 * 128]; // Z double buffer / f32 scratch
  __shared__ __align__(16) float wl_s[192];
  __shared__ float s_s[64];

  const int tid = threadIdx.x;
  const int lane = tid & 63;
  const int wv = tid >> 6;
  const int bid = blockIdx.x;

  if (tid < 192) wl_s[tid] = wl[tid];

  {  // stage x: 4 b's, layout (b_l, m, d4)
    const float4* xg = (const float4*)(x + (size_t)bid * 2560);
    for (int i = tid; i < 640; i += 256) {
      float4 v = xg[i];
      int d4 = (i & 3) << 2;
      int m = (i >> 2) % 40;
      int b_l = i / 160;
      int nb = b_l * 16 + d4;
      XP_s[xp_idx(nb + 0, m)] = v.x;
      XP_s[xp_idx(nb + 1, m)] = v.y;
      XP_s[xp_idx(nb + 2, m)] = v.z;
      XP_s[xp_idx(nb + 3, m)] = v.w;
      *(float4*)&XT_s[m * 64 + nb] = v;
    }
  }

  // Z-build mapping
  const int zn = tid & 63;
  const int zc = wv;
  const int sw4 = (zn & 7) << 2;
  const int xpb = zn << 6;
  const int zw0 = z_idx(zn, zc * 8);        // chunk zc
  const int zw1 = z_idx(zn, zc * 8 + 32);   // chunk zc+4
  const int zw2 = z_idx(zn, zc * 8 + 64);   // chunk zc+8  (BK=128 only)
  const int zw3 = z_idx(zn, zc * 8 + 96);   // chunk zc+12 (BK=128 only)

  // MFMA mapping
  const int nlo = lane & 15;
  const int kgrp = (lane >> 4) << 3;
  const int orow = (lane >> 4) << 2;
  const int swz3 = (nlo & 7) << 3;
  const int ohalf = wv & 1;
  const int khalf = wv >> 1;
  const int obase = ohalf << 6;
  const int rowb = nlo << 7;                               // + fn*2048
  const int kL0  = ((khalf << 5) + kgrp) ^ swz3;           // BK=64 k-offset
  const int k12a = ((khalf << 6) + kgrp) ^ swz3;           // BK=128 s=0
  const int k12b = ((khalf << 6) + 32 + kgrp) ^ swz3;      // BK=128 s=1

  f32x4 acc[4][4];
  float sacc[4] = {0.f, 0.f, 0.f, 0.f};
  const unsigned short* wb[4];

  auto set_layer_w = [&](const unsigned short* W, int K, int kbase) {
#pragma unroll
    for (int mr = 0; mr < 4; ++mr)
      wb[mr] = W + (size_t)(obase + mr * 16 + nlo) * K + kbase + kgrp;
  };
  auto zero_acc = [&]() {
#pragma unroll
    for (int a = 0; a < 4; ++a)
#pragma unroll
      for (int b = 0; b < 4; ++b) acc[a][b] = f32x4{0.f, 0.f, 0.f, 0.f};
  };
  auto mfma4 = [&](const unsigned short* zb, int kx, bf16x8 (&A)[4]) {
    const unsigned short* r = zb + rowb + kx;
#pragma unroll
    for (int fn = 0; fn < 4; ++fn) {
      bf16x8 bf = *(const bf16x8*)(r + fn * 2048);
#pragma unroll
      for (int mr = 0; mr < 4; ++mr) acc[mr][fn] = MFMA(A[mr], bf, acc[mr][fn]);
    }
  };

  // epilogue: cross-k pair reduction via LDS scratch, then bias/relu -> P or sacc
  auto epilogue = [&](int lidx, const float* bias) {
    float* scr = ohalf ? (float*)XP_s : (float*)Z_s;
    const bool live = (lidx < 2) || (ohalf == 1);
    if (khalf == 1 && live) {
#pragma unroll
      for (int mr = 0; mr < 4; ++mr)
#pragma unroll
        for (int fn = 0; fn < 4; ++fn)
          *(f32x4*)&scr[(mr * 4 + fn) * 256 + lane * 4] = acc[mr][fn];
    }
    __syncthreads();
    if (khalf == 0 && live) {
#pragma unroll
      for (int mr = 0; mr < 4; ++mr)
#pragma unroll
        for (int fn = 0; fn < 4; ++fn)
          acc[mr][fn] += *(const f32x4*)&scr[(mr * 4 + fn) * 256 + lane * 4];
    }
    __syncthreads();
    if (khalf == 0 && live) {
      if (ohalf == 0) {
#pragma unroll
        for (int mr = 0; mr < 4; ++mr) {
          const int o0 = mr * 16 + orow;
          float4 bv = *(const float4*)&bias[o0];
#pragma unroll
          for (int fn = 0; fn < 4; ++fn) {
            f32x4 a = acc[mr][fn];
            float4 r;
            r.x = fmaxf(a[0] + bv.x, 0.f);
            r.y = fmaxf(a[1] + bv.y, 0.f);
            r.z = fmaxf(a[2] + bv.z, 0.f);
            r.w = fmaxf(a[3] + bv.w, 0.f);
            *(float4*)&XP_s[xp_idx(fn * 16 + nlo, o0)] = r;
          }
        }
      } else {
#pragma unroll
        for (int mr = 0; mr < 4; ++mr) {
          const int o0 = 64 + mr * 16 + orow;
          float4 bv = *(const float4*)&bias[o0];
          float4 wv4 = *(const float4*)&wl_s[lidx * 64 + (o0 - 64)];
#pragma unroll
          for (int fn = 0; fn < 4; ++fn) {
            f32x4 a = acc[mr][fn];
            sacc[fn] += fmaxf(a[0] + bv.x, 0.f) * wv4.x
                      + fmaxf(a[1] + bv.y, 0.f) * wv4.y
                      + fmaxf(a[2] + bv.z, 0.f) * wv4.z
                      + fmaxf(a[3] + bv.w, 0.f) * wv4.w;
          }
        }
      }
    }
    __syncthreads();
  };

  __syncthreads();  // staging done

  // ================= layer 0: BK=64, P = X from LDS, A prefetch =================
  {
    set_layer_w(Wp, 1600, khalf << 5);
    zero_acc();
    f32x4 P0[4], P1[4];
    float X0[2], X1[2];
    bf16x8 A0[4], A1[4];
    auto aloadL0 = [&](int kt, bf16x8 (&A)[4]) {
      const int off = kt << 6;
#pragma unroll
      for (int mr = 0; mr < 4; ++mr) A[mr] = *(const bf16x8*)(wb[mr] + off);
    };
    auto pxload0 = [&](int ks, f32x4 (&Pp)[4], float (&Xp)[2]) {
      const int kk0 = (ks << 6) + (zc << 3);
      const int kk1 = kk0 + 32;
      const int m0 = kk0 / 40, h0 = kk0 - m0 * 40;
      const int m1 = kk1 / 40, h1 = kk1 - m1 * 40;
      Pp[0] = *(const f32x4*)&XP_s[xpb + (h0 ^ sw4)];
      Pp[1] = *(const f32x4*)&XP_s[xpb + ((h0 + 4) ^ sw4)];
      Pp[2] = *(const f32x4*)&XP_s[xpb + (h1 ^ sw4)];
      Pp[3] = *(const f32x4*)&XP_s[xpb + ((h1 + 4) ^ sw4)];
      Xp[0] = XT_s[(m0 << 6) + zn];
      Xp[1] = XT_s[(m1 << 6) + zn];
    };
    auto zstore0 = [&](unsigned short* zb, f32x4 (&Pp)[4], float (&Xp)[2]) {
      uint4 u0, u1;
      u0.x = cvt2(Pp[0][0] * Xp[0], Pp[0][1] * Xp[0]);
      u0.y = cvt2(Pp[0][2] * Xp[0], Pp[0][3] * Xp[0]);
      u0.z = cvt2(Pp[1][0] * Xp[0], Pp[1][1] * Xp[0]);
      u0.w = cvt2(Pp[1][2] * Xp[0], Pp[1][3] * Xp[0]);
      u1.x = cvt2(Pp[2][0] * Xp[1], Pp[2][1] * Xp[1]);
      u1.y = cvt2(Pp[2][2] * Xp[1], Pp[2][3] * Xp[1]);
      u1.z = cvt2(Pp[3][0] * Xp[1], Pp[3][1] * Xp[1]);
      u1.w = cvt2(Pp[3][2] * Xp[1], Pp[3][3] * Xp[1]);
      *(uint4*)(zb + zw0) = u0;
      *(uint4*)(zb + zw1) = u1;
    };
    aloadL0(0, A0);
    pxload0(0, P0, X0);
    zstore0(Z_s[0], P0, X0);
    pxload0(1, P1, X1);
    pxload0(2, P0, X0);
    __syncthreads();
    for (int kt = 0; kt < 25; kt += 2) {
      {
        aloadL0(kt + 1 < 25 ? kt + 1 : 24, A1);
        if (kt + 1 < 25) zstore0(Z_s[1], P1, X1);
        if (kt + 3 < 25) pxload0(kt + 3, P1, X1);
        mfma4(Z_s[0], kL0, A0);
        __syncthreads();
      }
      if (kt + 1 < 25) {
        aloadL0(kt + 2 < 25 ? kt + 2 : 24, A0);
        if (kt + 2 < 25) zstore0(Z_s[0], P0, X0);
        if (kt + 4 < 25) pxload0(kt + 4, P0, X0);
        mfma4(Z_s[1], kL0, A1);
        __syncthreads();
      }
    }
    epilogue(0, bias0);
  }

  // ================= layers 1,2: BK=128, P in regs, A prefetch =================
  for (int lidx = 1; lidx < 3; ++lidx) {
    const unsigned short* W = (lidx == 1) ? (Wp + 204800) : (Wp + 532480);
    const float* bias = (lidx == 1) ? bias1 : bias2;
    set_layer_w(W, 2560, khalf << 6);
    zero_acc();
    f32x4 Pc[4];
    Pc[0] = *(const f32x4*)&XP_s[xpb + ((zc * 8) ^ sw4)];
    Pc[1] = *(const f32x4*)&XP_s[xpb + ((zc * 8 + 4) ^ sw4)];
    Pc[2] = *(const f32x4*)&XP_s[xpb + ((zc * 8 + 32) ^ sw4)];
    Pc[3] = *(const f32x4*)&XP_s[xpb + ((zc * 8 + 36) ^ sw4)];
    bf16x8 Aa[4], Ab[4];
    auto aload12 = [&](int kt, int s, bf16x8 (&A)[4]) {
      const int off = (kt << 7) + (s << 5);
#pragma unroll
      for (int mr = 0; mr < 4; ++mr) A[mr] = *(const bf16x8*)(wb[mr] + off);
    };
    auto zstore12 = [&](unsigned short* zb, float xa, float xb) {
      uint4 u0, u1, u2, u3;
      u0.x = cvt2(Pc[0][0] * xa, Pc[0][1] * xa);
      u0.y = cvt2(Pc[0][2] * xa, Pc[0][3] * xa);
      u0.z = cvt2(Pc[1][0] * xa, Pc[1][1] * xa);
      u0.w = cvt2(Pc[1][2] * xa, Pc[1][3] * xa);
      u1.x = cvt2(Pc[2][0] * xa, Pc[2][1] * xa);
      u1.y = cvt2(Pc[2][2] * xa, Pc[2][3] * xa);
      u1.z = cvt2(Pc[3][0] * xa, Pc[3][1] * xa);
      u1.w = cvt2(Pc[3][2] * xa, Pc[3][3] * xa);
      u2.x = cvt2(Pc[0][0] * xb, Pc[0][1] * xb);
      u2.y = cvt2(Pc[0][2] * xb, Pc[0][3] * xb);
      u2.z = cvt2(Pc[1][0] * xb, Pc[1][1] * xb);
      u2.w = cvt2(Pc[1][2] * xb, Pc[1][3] * xb);
      u3.x = cvt2(Pc[2][0] * xb, Pc[2][1] * xb);
      u3.y = cvt2(Pc[2][2] * xb, Pc[2][3] * xb);
      u3.z = cvt2(Pc[3][0] * xb, Pc[3][1] * xb);
      u3.w = cvt2(Pc[3][2] * xb, Pc[3][3] * xb);
      *(uint4*)(zb + zw0) = u0;
      *(uint4*)(zb + zw1) = u1;
      *(uint4*)(zb + zw2) = u2;
      *(uint4*)(zb + zw3) = u3;
    };
    aload12(0, 0, Aa);
    aload12(0, 1, Ab);
    float xvA = XT_s[zn];           // m = 0
    float xvB = XT_s[64 + zn];      // m = 1
    zstore12(Z_s[0], xvA, xvB);
    float xvA2 = XT_s[128 + zn];    // m = 2
    float xvB2 = XT_s[192 + zn];    // m = 3
    __syncthreads();
    for (int kt = 0; kt < 20; kt += 2) {
      {  // even step: compute Z_s[0], build Z_s[1]
        zstore12(Z_s[1], xvA2, xvB2);                    // pair for kt+1 (kt+1 <= 19 always)
        if (kt + 2 < 20) {
          xvA2 = XT_s[(((kt + 2) << 1) << 6) + zn];
          xvB2 = XT_s[((((kt + 2) << 1) + 1) << 6) + zn];
        }
        mfma4(Z_s[0], k12a, Aa);
        aload12(kt + 1, 0, Aa);
        mfma4(Z_s[0], k12b, Ab);
        aload12(kt + 1, 1, Ab);
        __syncthreads();
      }
      {  // odd step: compute Z_s[1], build Z_s[0]
        if (kt + 2 < 20) {
          zstore12(Z_s[0], xvA2, xvB2);                  // pair for kt+2
          if (kt + 3 < 20) {
            xvA2 = XT_s[(((kt + 3) << 1) << 6) + zn];
            xvB2 = XT_s[((((kt + 3) << 1) + 1) << 6) + zn];
          }
        }
        const int ktn = (kt + 2 < 20) ? kt + 2 : 19;
        mfma4(Z_s[1], k12a, Aa);
        aload12(ktn, 0, Aa);
        mfma4(Z_s[1], k12b, Ab);
        aload12(ktn, 1, Ab);
        __syncthreads();
      }
    }
    epilogue(lidx, bias);
  }

  // ================= head =================
#pragma unroll
  for (int fn = 0; fn < 4; ++fn) {
    float v = sacc[fn];
    v += __shfl_xor(v, 16);
    v += __shfl_xor(v, 32);
    if (wv == 1 && lane < 16) s_s[fn * 16 + lane] = v;
  }
  __syncthreads();
  if (tid < 4) {
    float s = 0.f;
#pragma unroll
    for (int d = 0; d < 16; ++d) s += s_s[tid * 16 + d];
    out[bid * 4 + tid] = s;
  }
}

extern "C" void kernel_launch(void* const* d_in, const int* in_sizes, int n_in,
                              void* d_out, int out_size, void* d_ws, size_t ws_size,
                              hipStream_t stream) {
  const float* x  = (const float*)d_in[0];
  const float* w0 = (const float*)d_in[1];
  const float* b0 = (const float*)d_in[2];
  const float* w1 = (const float*)d_in[3];
  const float* b1 = (const float*)d_in[4];
  const float* w2 = (const float*)d_in[5];
  const float* b2 = (const float*)d_in[6];
  const float* wl = (const float*)d_in[7];
  unsigned short* Wp = (unsigned short*)d_ws;  // 860160 bf16 = 1.72 MB

  permute_w_kernel<<<384, 256, 0, stream>>>(w0, w1, w2, Wp);
  cin_kernel<<<512, 256, 0, stream>>>(x, Wp, b0, b1, b2, wl, (float*)d_out);
}

// Round 4
// 160.516 us; speedup vs baseline: 1.0775x; 1.0775x over previous
//
#include <hip/hip_runtime.h>
#include <hip/hip_bf16.h>

typedef short bf16x8 __attribute__((ext_vector_type(8)));
typedef float f32x4  __attribute__((ext_vector_type(4)));

__device__ __forceinline__ unsigned cvt2(float a, float b) {
  __hip_bfloat162 h = __float22bfloat162_rn(make_float2(a, b));
  unsigned u; __builtin_memcpy(&u, &h, 4); return u;
}

__device__ __forceinline__ f32x4 MFMA(bf16x8 a, bf16x8 b, f32x4 c) {
  return __builtin_amdgcn_mfma_f32_16x16x32_bf16(a, b, c, 0, 0, 0);
}

// XP: [128 cols][64 h] f32, XOR swizzle at 4-word (16B) granule keyed on n&15
__device__ __forceinline__ int xp_idx(int n, int h) { return (n << 6) + (h ^ ((n & 15) << 2)); }

// ---- weight permute + bf16 cast via transposed padded LDS ----
// W'[o][k'] with k' = m*H + h, source w[o][h*40 + m]
__global__ __launch_bounds__(256) void permute_w_kernel(
    const float* __restrict__ w0, const float* __restrict__ w1,
    const float* __restrict__ w2, unsigned short* __restrict__ Wp) {
  __shared__ float rowt[40 * 65];   // [m][h], padded stride 65
  const int b = blockIdx.x;
  const float* src; unsigned short* dst; int K, LZ;
  if (b < 128)      { src = w0 + b * 1600;            dst = Wp + b * 1600;            K = 1600; LZ = 1; }
  else if (b < 256) { int o = b - 128; src = w1 + o * 2560; dst = Wp + 204800 + o * 2560; K = 2560; LZ = 0; }
  else              { int o = b - 256; src = w2 + o * 2560; dst = Wp + 532480 + o * 2560; K = 2560; LZ = 0; }
  for (int i = threadIdx.x; i < (K >> 2); i += 256) {
    float4 v = ((const float4*)src)[i];
    int f = i << 2;
    int h = f / 40, m = f - h * 40;   // src h-major, m inner; 4 | 40 so no straddle
    rowt[(m + 0) * 65 + h] = v.x;
    rowt[(m + 1) * 65 + h] = v.y;
    rowt[(m + 2) * 65 + h] = v.z;
    rowt[(m + 3) * 65 + h] = v.w;
  }
  __syncthreads();
  for (int i = threadIdx.x; i < (K >> 3); i += 256) {
    const int k = i << 3;
    int m, h;
    if (LZ) { m = k / 40; h = k - m * 40; } else { m = k >> 6; h = k & 63; }
    const float* p = &rowt[m * 65 + h];
    uint4 u;
    u.x = cvt2(p[0], p[1]); u.y = cvt2(p[2], p[3]);
    u.z = cvt2(p[4], p[5]); u.w = cvt2(p[6], p[7]);
    *(uint4*)&dst[k] = u;
  }
}

// ---- fused CIN: 128 columns (8 b x 16 d) per block, 8 waves, NO in-loop barriers ----
__global__ __launch_bounds__(512, 2) void cin_kernel(
    const float* __restrict__ x, const unsigned short* __restrict__ Wp,
    const float* __restrict__ bias0, const float* __restrict__ bias1,
    const float* __restrict__ bias2, const float* __restrict__ wl,
    float* __restrict__ out) {
  __shared__ __align__(16) float XP_s[128 * 64];   // 32KB: X (L0) then P
  __shared__ __align__(16) float XT_s[40 * 128];   // 20KB: X transposed [m][col]
  __shared__ __align__(16) float scr_s[4 * 4096];  // 64KB: epilogue khalf-reduction scratch
  __shared__ float wl_s[192];
  __shared__ float s_s[128];                       // per-column head accumulators

  const int tid = threadIdx.x;
  const int lane = tid & 63;
  const int wv = tid >> 6;
  const int bid = blockIdx.x;

  if (tid < 192) wl_s[tid] = wl[tid];
  if (tid < 128) s_s[tid] = 0.f;

  {  // stage x: 8 b's, global layout (b_l, m, d); write swizzled XP + transposed XT
    const float4* xg = (const float4*)(x + (size_t)bid * 5120);
    for (int i = tid; i < 1280; i += 512) {
      float4 v = xg[i];
      int d4 = (i & 3) << 2;
      int m = (i >> 2) % 40;
      int b_l = i / 160;
      int nb = b_l * 16 + d4;
      XP_s[xp_idx(nb + 0, m)] = v.x;
      XP_s[xp_idx(nb + 1, m)] = v.y;
      XP_s[xp_idx(nb + 2, m)] = v.z;
      XP_s[xp_idx(nb + 3, m)] = v.w;
      *(float4*)&XT_s[(m << 7) + nb] = v;
    }
  }

  const int nlo = lane & 15;
  const int q = lane >> 4;       // k-octet index within 32-k MFMA tile
  const int orow = q << 2;       // C-fragment row group
  const int swn = nlo << 2;      // XP swizzle key (n&15 == nlo for all our n)

  auto mkB = [&](const f32x4& pa, const f32x4& pb, float xv) -> bf16x8 {
    uint4 u;
    u.x = cvt2(pa[0] * xv, pa[1] * xv);
    u.y = cvt2(pa[2] * xv, pa[3] * xv);
    u.z = cvt2(pb[0] * xv, pb[1] * xv);
    u.w = cvt2(pb[2] * xv, pb[3] * xv);
    return __builtin_bit_cast(bf16x8, u);
  };

  __syncthreads();  // staging visible

  // ================= LAYER 0: waves = (ohalf, khalf, nhalf); BK=64, 25 steps =====
  {
    const int ohalf = wv & 1, khalf = (wv >> 1) & 1, nhalf = wv >> 2;
    const int obase = ohalf << 6;
    const int nf0 = (nhalf << 6) + nlo;
    const int k0 = (khalf << 5) + (q << 3);

    f32x4 acc[4][4];
#pragma unroll
    for (int a = 0; a < 4; ++a)
#pragma unroll
      for (int b = 0; b < 4; ++b) acc[a][b] = f32x4{0.f, 0.f, 0.f, 0.f};

    const unsigned short* wp[4];
#pragma unroll
    for (int mr = 0; mr < 4; ++mr)
      wp[mr] = Wp + (size_t)(obase + mr * 16 + nlo) * 1600 + k0;

    int m = (k0 >= 40) ? 1 : 0;
    int h = k0 - 40 * m;

    bf16x8 Aa[4], Ab[4];
#pragma unroll
    for (int mr = 0; mr < 4; ++mr) Aa[mr] = *(const bf16x8*)(wp[mr]);

    auto stepL0 = [&](bf16x8 (&A)[4]) {
#pragma unroll
      for (int fn = 0; fn < 4; ++fn) {
        const int nf = nf0 + fn * 16;
        const int rb = nf << 6;
        f32x4 pa = *(const f32x4*)&XP_s[rb + (h ^ swn)];
        f32x4 pb = *(const f32x4*)&XP_s[rb + ((h + 4) ^ swn)];
        float xv = XT_s[(m << 7) + nf];
        bf16x8 B = mkB(pa, pb, xv);
#pragma unroll
        for (int mr = 0; mr < 4; ++mr) acc[mr][fn] = MFMA(A[mr], B, acc[mr][fn]);
      }
      h += 24; ++m;
      if (h >= 40) { h -= 40; ++m; }
    };

    for (int s = 0; s < 24; s += 2) {
#pragma unroll
      for (int mr = 0; mr < 4; ++mr) Ab[mr] = *(const bf16x8*)(wp[mr] + (s + 1) * 64);
      stepL0(Aa);
#pragma unroll
      for (int mr = 0; mr < 4; ++mr) Aa[mr] = *(const bf16x8*)(wp[mr] + (s + 2) * 64);
      stepL0(Ab);
    }
    stepL0(Aa);  // s = 24

    // ---- epilogue L0: khalf-pair reduction, bias+relu -> P (o<64) / head (o>=64)
    const int pid = (nhalf << 1) | ohalf;
    __syncthreads();
    if (khalf == 1) {
#pragma unroll
      for (int mr = 0; mr < 4; ++mr)
#pragma unroll
        for (int fn = 0; fn < 4; ++fn)
          *(f32x4*)&scr_s[pid * 4096 + (mr * 4 + fn) * 256 + lane * 4] = acc[mr][fn];
    }
    __syncthreads();
    if (khalf == 0) {
#pragma unroll
      for (int mr = 0; mr < 4; ++mr)
#pragma unroll
        for (int fn = 0; fn < 4; ++fn)
          acc[mr][fn] += *(const f32x4*)&scr_s[pid * 4096 + (mr * 4 + fn) * 256 + lane * 4];
      if (ohalf == 0) {
#pragma unroll
        for (int mr = 0; mr < 4; ++mr) {
          const int o0 = mr * 16 + orow;
          float4 bv = *(const float4*)&bias0[o0];
#pragma unroll
          for (int fn = 0; fn < 4; ++fn) {
            f32x4 a = acc[mr][fn];
            float4 r;
            r.x = fmaxf(a[0] + bv.x, 0.f);
            r.y = fmaxf(a[1] + bv.y, 0.f);
            r.z = fmaxf(a[2] + bv.z, 0.f);
            r.w = fmaxf(a[3] + bv.w, 0.f);
            *(float4*)&XP_s[xp_idx(nf0 + fn * 16, o0)] = r;
          }
        }
      } else {
        float dir[4] = {0.f, 0.f, 0.f, 0.f};
#pragma unroll
        for (int mr = 0; mr < 4; ++mr) {
          const int o0 = 64 + mr * 16 + orow;
          float4 bv = *(const float4*)&bias0[o0];
          float4 wv4 = *(const float4*)&wl_s[o0 - 64];
#pragma unroll
          for (int fn = 0; fn < 4; ++fn) {
            f32x4 a = acc[mr][fn];
            dir[fn] += fmaxf(a[0] + bv.x, 0.f) * wv4.x
                     + fmaxf(a[1] + bv.y, 0.f) * wv4.y
                     + fmaxf(a[2] + bv.z, 0.f) * wv4.z
                     + fmaxf(a[3] + bv.w, 0.f) * wv4.w;
          }
        }
#pragma unroll
        for (int fn = 0; fn < 4; ++fn) {
          float v = dir[fn];
          v += __shfl_xor(v, 16);
          v += __shfl_xor(v, 32);
          if (lane < 16) atomicAdd(&s_s[(nhalf << 6) + fn * 16 + lane], v);
        }
      }
    }
    __syncthreads();  // new P visible
  }

  // ================= LAYERS 1,2: waves = (oq, khalf); BK=64, 40 steps ===========
  for (int lidx = 1; lidx < 3; ++lidx) {
    const unsigned short* W = (lidx == 1) ? (Wp + 204800) : (Wp + 532480);
    const float* bias = (lidx == 1) ? bias1 : bias2;
    const int oq = wv >> 1, khalf = wv & 1;
    const int obase = oq << 5;
    const int h0 = (khalf << 5) + (q << 3);

    // P register cache: constant h-octet per thread, 8 n-columns
    f32x4 Pc[8][2];
#pragma unroll
    for (int fn = 0; fn < 8; ++fn) {
      const int rb = (fn * 16 + nlo) << 6;
      Pc[fn][0] = *(const f32x4*)&XP_s[rb + (h0 ^ swn)];
      Pc[fn][1] = *(const f32x4*)&XP_s[rb + ((h0 + 4) ^ swn)];
    }

    f32x4 acc[2][8];
#pragma unroll
    for (int a = 0; a < 2; ++a)
#pragma unroll
      for (int b = 0; b < 8; ++b) acc[a][b] = f32x4{0.f, 0.f, 0.f, 0.f};

    const unsigned short* wp[2];
#pragma unroll
    for (int mr = 0; mr < 2; ++mr)
      wp[mr] = W + (size_t)(obase + mr * 16 + nlo) * 2560 + h0;

    bf16x8 Aa[2], Ab[2];
#pragma unroll
    for (int mr = 0; mr < 2; ++mr) Aa[mr] = *(const bf16x8*)(wp[mr]);

    for (int s = 0; s < 40; s += 2) {
#pragma unroll
      for (int mr = 0; mr < 2; ++mr) Ab[mr] = *(const bf16x8*)(wp[mr] + 64);
#pragma unroll
      for (int fn = 0; fn < 8; ++fn) {
        float xv = XT_s[(s << 7) + fn * 16 + nlo];
        bf16x8 B = mkB(Pc[fn][0], Pc[fn][1], xv);
        acc[0][fn] = MFMA(Aa[0], B, acc[0][fn]);
        acc[1][fn] = MFMA(Aa[1], B, acc[1][fn]);
      }
      const int offn = (s + 2 < 40) ? 128 : 64;
#pragma unroll
      for (int mr = 0; mr < 2; ++mr) Aa[mr] = *(const bf16x8*)(wp[mr] + offn);
#pragma unroll
      for (int fn = 0; fn < 8; ++fn) {
        float xv = XT_s[((s + 1) << 7) + fn * 16 + nlo];
        bf16x8 B = mkB(Pc[fn][0], Pc[fn][1], xv);
        acc[0][fn] = MFMA(Ab[0], B, acc[0][fn]);
        acc[1][fn] = MFMA(Ab[1], B, acc[1][fn]);
      }
      wp[0] += 128; wp[1] += 128;
    }

    // ---- epilogue: khalf-pair reduction; oq<2 -> P (if lidx<2), oq>=2 -> head
    __syncthreads();
    if (khalf == 1) {
#pragma unroll
      for (int mr = 0; mr < 2; ++mr)
#pragma unroll
        for (int fn = 0; fn < 8; ++fn)
          *(f32x4*)&scr_s[oq * 4096 + (mr * 8 + fn) * 256 + lane * 4] = acc[mr][fn];
    }
    __syncthreads();
    if (khalf == 0) {
#pragma unroll
      for (int mr = 0; mr < 2; ++mr)
#pragma unroll
        for (int fn = 0; fn < 8; ++fn)
          acc[mr][fn] += *(const f32x4*)&scr_s[oq * 4096 + (mr * 8 + fn) * 256 + lane * 4];
      if (oq < 2) {
        if (lidx < 2) {
#pragma unroll
          for (int mr = 0; mr < 2; ++mr) {
            const int o0 = obase + mr * 16 + orow;
            float4 bv = *(const float4*)&bias[o0];
#pragma unroll
            for (int fn = 0; fn < 8; ++fn) {
              f32x4 a = acc[mr][fn];
              float4 r;
              r.x = fmaxf(a[0] + bv.x, 0.f);
              r.y = fmaxf(a[1] + bv.y, 0.f);
              r.z = fmaxf(a[2] + bv.z, 0.f);
              r.w = fmaxf(a[3] + bv.w, 0.f);
              *(float4*)&XP_s[xp_idx(fn * 16 + nlo, o0)] = r;
            }
          }
        }
      } else {
        float dir[8] = {0.f, 0.f, 0.f, 0.f, 0.f, 0.f, 0.f, 0.f};
#pragma unroll
        for (int mr = 0; mr < 2; ++mr) {
          const int o0 = 64 + (oq - 2) * 32 + mr * 16 + orow;
          float4 bv = *(const float4*)&bias[o0];
          float4 wv4 = *(const float4*)&wl_s[lidx * 64 + (o0 - 64)];
#pragma unroll
          for (int fn = 0; fn < 8; ++fn) {
            f32x4 a = acc[mr][fn];
            dir[fn] += fmaxf(a[0] + bv.x, 0.f) * wv4.x
                     + fmaxf(a[1] + bv.y, 0.f) * wv4.y
                     + fmaxf(a[2] + bv.z, 0.f) * wv4.z
                     + fmaxf(a[3] + bv.w, 0.f) * wv4.w;
          }
        }
#pragma unroll
        for (int fn = 0; fn < 8; ++fn) {
          float v = dir[fn];
          v += __shfl_xor(v, 16);
          v += __shfl_xor(v, 32);
          if (lane < 16) atomicAdd(&s_s[fn * 16 + lane], v);
        }
      }
    }
    __syncthreads();
  }

  // ================= head: out[b] = sum over d of per-column scalars ============
  if (tid < 8) {
    float s = 0.f;
#pragma unroll
    for (int d = 0; d < 16; ++d) s += s_s[tid * 16 + d];
    out[bid * 8 + tid] = s;
  }
}

extern "C" void kernel_launch(void* const* d_in, const int* in_sizes, int n_in,
                              void* d_out, int out_size, void* d_ws, size_t ws_size,
                              hipStream_t stream) {
  const float* x  = (const float*)d_in[0];
  const float* w0 = (const float*)d_in[1];
  const float* b0 = (const float*)d_in[2];
  const float* w1 = (const float*)d_in[3];
  const float* b1 = (const float*)d_in[4];
  const float* w2 = (const float*)d_in[5];
  const float* b2 = (const float*)d_in[6];
  const float* wl = (const float*)d_in[7];
  unsigned short* Wp = (unsigned short*)d_ws;  // 860160 bf16 = 1.72 MB

  permute_w_kernel<<<384, 256, 0, stream>>>(w0, w1, w2, Wp);
  cin_kernel<<<256, 512, 0, stream>>>(x, Wp, b0, b1, b2, wl, (float*)d_out);
}